// Round 1
// baseline (161.679 us; speedup 1.0000x reference)
//
#include <hip/hip_runtime.h>
#include <cstddef>
#include <cstdint>

typedef float  f32x4  __attribute__((ext_vector_type(4)));
typedef float  f32x16 __attribute__((ext_vector_type(16)));
typedef __bf16 bf16x8 __attribute__((ext_vector_type(8)));
typedef unsigned short ushort_t;
typedef unsigned int __attribute__((address_space(1))) u32_g;
typedef unsigned int __attribute__((address_space(3))) u32_l;

#define S_LEN  2048
#define DMODEL 1024
#define NH     16
#define QKV_LD 3072   // fused QKV row stride (Q|K|V)

static __device__ __forceinline__ ushort_t f2bf(float f) {
    union { float f; unsigned u; } v; v.f = f;
    unsigned r = (v.u + 0x7FFFu + ((v.u >> 16) & 1u)) >> 16;
    return (ushort_t)r;
}
static __device__ __forceinline__ float bf2f(ushort_t b) {
    union { unsigned u; float f; } v; v.u = ((unsigned)b) << 16;
    return v.f;
}
// pack two f32 -> 2xbf16 dword (compiler emits v_cvt_pk_bf16_f32)
static __device__ __forceinline__ unsigned cvtpk(float a, float b) {
    union { __bf16 h[2]; unsigned u; } t;
    t.h[0] = (__bf16)a; t.h[1] = (__bf16)b;
    return t.u;
}
// async 16B global->LDS; lds dst = wave-uniform base + lane*16
static __device__ __forceinline__ void load_lds16(const void* g, void* l) {
    __builtin_amdgcn_global_load_lds((const u32_g*)g, (u32_l*)l, 16, 0, 0);
}
static __device__ __forceinline__ int rel_bucket(int rp) {
    int arp = rp < 0 ? -rp : rp;
    int bucket;
    if (arp < 8) bucket = arp;
    else { int lg = 33 - __clz(arp * arp); bucket = lg < 15 ? lg : 15; }
    return rp > 0 ? bucket + 16 : bucket;
}

// ---------------- cast X (fp32 -> bf16), elementwise ----------------
__global__ __launch_bounds__(256) void cast_x(const float* __restrict__ X,
                                              ushort_t* __restrict__ Xb, int n4) {
    int i = blockIdx.x * 256 + threadIdx.x;
    if (i < n4) {
        float4 v = ((const float4*)X)[i];
        ushort4 o = make_ushort4(f2bf(v.x), f2bf(v.y), f2bf(v.z), f2bf(v.w));
        ((ushort4*)Xb)[i] = o;
    }
}

// ------------- weight transpose+cast: W[k][n] fp32 -> W^T[n][k] bf16 -------------
__global__ __launch_bounds__(256) void wcast(
    const float* __restrict__ Wq, const float* __restrict__ Wk,
    const float* __restrict__ Wv, const float* __restrict__ Wo,
    ushort_t* __restrict__ Wt, ushort_t* __restrict__ Wot)
{
    __shared__ float T[64][68];
    const int z = blockIdx.z;
    const float* W = (z == 0) ? Wq : (z == 1) ? Wk : (z == 2) ? Wv : Wo;
    ushort_t* Out = (z == 3) ? Wot : (Wt + (size_t)z * 1024 * 1024);
    const int k0 = blockIdx.y * 64, n0 = blockIdx.x * 64;
    const int t = threadIdx.x;
    #pragma unroll
    for (int i = 0; i < 4; i++) {
        int g = i * 256 + t; int kl = g >> 4, ng = g & 15;
        float4 v = *(const float4*)&W[(size_t)(k0 + kl) * 1024 + n0 + ng * 4];
        *(float4*)&T[kl][ng * 4] = v;
    }
    __syncthreads();
    #pragma unroll
    for (int i = 0; i < 2; i++) {
        int g = i * 256 + t; int nl = g >> 3, kg = g & 7;
        alignas(16) ushort_t pk[8];
        #pragma unroll
        for (int j = 0; j < 8; j++) pk[j] = f2bf(T[kg * 8 + j][nl]);
        *(uint4*)&Out[(size_t)(n0 + nl) * 1024 + k0 + kg * 8] = *(uint4*)pk;
    }
}

// ------------- per-head V transpose: QKV V-section -> Vt[h][d][s] bf16 -------------
__global__ __launch_bounds__(256) void vt_trans(const ushort_t* __restrict__ QKV,
                                                ushort_t* __restrict__ Vt) {
    __shared__ ushort_t T[64][80];
    const int h = blockIdx.y, s0 = blockIdx.x * 64;
    const int t = threadIdx.x;
    #pragma unroll
    for (int i = 0; i < 2; i++) {
        int g = i * 256 + t; int sl = g >> 3, dg = g & 7;
        *(uint4*)&T[sl][dg * 8] =
            *(const uint4*)&QKV[(size_t)(s0 + sl) * QKV_LD + 2048 + h * 64 + dg * 8];
    }
    __syncthreads();
    #pragma unroll
    for (int i = 0; i < 2; i++) {
        int g = i * 256 + t; int dl = g >> 3, sg = g & 7;
        alignas(16) ushort_t pk[8];
        #pragma unroll
        for (int j = 0; j < 8; j++) pk[j] = T[sg * 8 + j][dl];
        *(uint4*)&Vt[(size_t)(h * 64 + dl) * S_LEN + s0 + sg * 8] = *(uint4*)pk;
    }
}

// ---------------- bf16 MFMA GEMM 128x128 (QKV projection) ----------------
__global__ __launch_bounds__(256) void gemm_bf16(
    const ushort_t* __restrict__ A, const ushort_t* __restrict__ B,
    ushort_t* __restrict__ Cout, int M, int N, int K)
{
    __shared__ ushort_t As[128 * 64];
    __shared__ ushort_t Bs[128 * 64];
    const int tid = threadIdx.x;
    const int w = tid >> 6, lane = tid & 63, quad = lane >> 4, cid = lane & 15;
    const int wm = w >> 1, wn = w & 1;
    const int m0 = blockIdx.y * 128, n0 = blockIdx.x * 128;

    f32x4 acc[4][4] = {};

    for (int k0 = 0; k0 < K; k0 += 64) {
        #pragma unroll
        for (int i = 0; i < 4; i++) {
            int g = i * 256 + tid; int r = g >> 3, kg = g & 7;
            int dg = kg ^ (r & 7);
            load_lds16(A + (size_t)(m0 + r) * K + k0 + dg * 8, &As[(i * 256 + w * 64) * 8]);
            load_lds16(B + (size_t)(n0 + r) * K + k0 + dg * 8, &Bs[(i * 256 + w * 64) * 8]);
        }
        __syncthreads();
        #pragma unroll
        for (int kk = 0; kk < 2; kk++) {
            bf16x8 af[4], bf[4];
            #pragma unroll
            for (int t = 0; t < 4; t++) {
                int m = wm * 64 + t * 16 + cid;
                af[t] = *(const bf16x8*)&As[m * 64 + (((kk * 4 + quad) ^ (m & 7)) * 8)];
                int n = wn * 64 + t * 16 + cid;
                bf[t] = *(const bf16x8*)&Bs[n * 64 + (((kk * 4 + quad) ^ (n & 7)) * 8)];
            }
            #pragma unroll
            for (int i = 0; i < 4; i++)
                #pragma unroll
                for (int j = 0; j < 4; j++)
                    acc[i][j] = __builtin_amdgcn_mfma_f32_16x16x32_bf16(af[i], bf[j], acc[i][j], 0, 0, 0);
        }
        __syncthreads();
    }
    #pragma unroll
    for (int i = 0; i < 4; i++)
        #pragma unroll
        for (int j = 0; j < 4; j++)
            #pragma unroll
            for (int r = 0; r < 4; r++) {
                int row = m0 + wm * 64 + i * 16 + quad * 4 + r;
                int col = n0 + wn * 64 + j * 16 + cid;
                Cout[(size_t)row * N + col] = f2bf(acc[i][j][r]);
            }
}

// ---------------- bf16 MFMA GEMM 64x64, fp32 out (output projection) ----------------
__global__ __launch_bounds__(256) void gemm64_f32(
    const ushort_t* __restrict__ A, const ushort_t* __restrict__ B,
    float* __restrict__ Cout, int M, int N, int K)
{
    __shared__ ushort_t As[64 * 64];
    __shared__ ushort_t Bs[64 * 64];
    const int tid = threadIdx.x;
    const int w = tid >> 6, lane = tid & 63, quad = lane >> 4, cid = lane & 15;
    const int wm = w >> 1, wn = w & 1;
    const int m0 = blockIdx.y * 64, n0 = blockIdx.x * 64;

    f32x4 acc[2][2] = {};

    for (int k0 = 0; k0 < K; k0 += 64) {
        #pragma unroll
        for (int i = 0; i < 2; i++) {
            int g = i * 256 + tid; int r = g >> 3, kg = g & 7;
            int dg = kg ^ (r & 7);
            load_lds16(A + (size_t)(m0 + r) * K + k0 + dg * 8, &As[(i * 256 + w * 64) * 8]);
            load_lds16(B + (size_t)(n0 + r) * K + k0 + dg * 8, &Bs[(i * 256 + w * 64) * 8]);
        }
        __syncthreads();
        #pragma unroll
        for (int kk = 0; kk < 2; kk++) {
            bf16x8 af[2], bf[2];
            #pragma unroll
            for (int t = 0; t < 2; t++) {
                int m = wm * 32 + t * 16 + cid;
                af[t] = *(const bf16x8*)&As[m * 64 + (((kk * 4 + quad) ^ (m & 7)) * 8)];
                int n = wn * 32 + t * 16 + cid;
                bf[t] = *(const bf16x8*)&Bs[n * 64 + (((kk * 4 + quad) ^ (n & 7)) * 8)];
            }
            #pragma unroll
            for (int i = 0; i < 2; i++)
                #pragma unroll
                for (int j = 0; j < 2; j++)
                    acc[i][j] = __builtin_amdgcn_mfma_f32_16x16x32_bf16(af[i], bf[j], acc[i][j], 0, 0, 0);
        }
        __syncthreads();
    }
    #pragma unroll
    for (int i = 0; i < 2; i++)
        #pragma unroll
        for (int j = 0; j < 2; j++)
            #pragma unroll
            for (int r = 0; r < 4; r++) {
                int row = m0 + wm * 32 + i * 16 + quad * 4 + r;
                int col = n0 + wn * 32 + j * 16 + cid;
                Cout[(size_t)row * N + col] = acc[i][j][r];
            }
}

// ---------------- MFMA flash attention, 32x32x16, fixed-max (m=0), split-K=2 ------
// Grid (32, 16, 2): q-tile(64), head, K-segment of 1024. Block: 4 waves =
// 2 q-subtiles (wq, 32 rows) x 2 key-halves (wk, 32 keys of each 64-chunk).
// Swapped QK^T: S^T = mfma(K, Q) -> lane holds P-row slice for q = lane&31;
// P->A-fragment built in-register via cvt_pk + v_permlane32_swap (no Ps LDS).
// Bias enters via MFMA C-operand init. Key-halves combined in LDS at the end.
__global__ __launch_bounds__(256) void attn_mfma(
    const ushort_t* __restrict__ QKV, const ushort_t* __restrict__ Vt,
    const float* __restrict__ rel_bias,
    ushort_t* __restrict__ Opart, float* __restrict__ Lpart)
{
    __shared__ float    tab[1088];       // bias over this block's rp span, 4.25 KB
    __shared__ ushort_t KV[2][64 * 64];  // [0]=K chunk [key][d^], [1]=V chunk [d][key^], 16 KB
    __shared__ float    Lsh[64];

    const int tid = threadIdx.x;
    const int w = tid >> 6, lane = tid & 63;
    const int cid32 = lane & 31, hi = lane >> 5;
    const int wq = w >> 1, wk = w & 1;
    const int h = blockIdx.y, q0 = blockIdx.x * 64;
    const int seg = blockIdx.z, s0 = seg * 1024;

    // bias table for rp = k - q in [s0 - q0 - 63, s0 + 1023 - q0]
    const int rpmin = s0 - q0 - 63;
    for (int idx = tid; idx < 1087; idx += 256)
        tab[idx] = rel_bias[rel_bucket(rpmin + idx) * NH + h];

    // Q fragments (B operand of swapped QK^T): row q = cid32, k(d) = s*16 + hi*8 + j
    const int qg = q0 + wq * 32 + cid32;
    bf16x8 qf[4];
    #pragma unroll
    for (int s = 0; s < 4; s++)
        qf[s] = *(const bf16x8*)&QKV[(size_t)qg * QKV_LD + h * 64 + s * 16 + hi * 8];

    bf16x8 vones;
    {
        union { ushort_t u; __bf16 b; } c; c.u = 0x3F80;  // bf16 1.0
        #pragma unroll
        for (int i = 0; i < 8; i++) vones[i] = c.b;
    }

    f32x16 Oacc[2] = {};   // [dt]: rows q=rowmap(r), col d = dt*32+cid32
    f32x16 Lacc = {};      // rows q=rowmap(r), all cols identical

    // tab base: idx = (k0-s0) + wk*32 + 4*hi + 63 - wq*32 - cid32 + (r&3)+8*(r>>2)
    const float* tb0 = &tab[wk * 32 + 4 * hi + 63 - wq * 32 - cid32];
    const int krow = wk * 32 + cid32;    // Ks row this lane reads (A operand)
    const int kxor = krow & 7;

    for (int k0 = s0; k0 < s0 + 1024; k0 += 64) {
        __syncthreads();   // prior chunk's KV reads done (1st iter: tab init)
        #pragma unroll
        for (int i = 0; i < 2; i++) {
            int g = i * 256 + tid; int row = g >> 3, kg = g & 7;
            int dg = kg ^ (row & 7);
            load_lds16(QKV + (size_t)(k0 + row) * QKV_LD + 1024 + h * 64 + dg * 8,
                       &KV[0][(i * 256 + w * 64) * 8]);
            load_lds16(Vt + (size_t)(h * 64 + row) * S_LEN + k0 + dg * 8,
                       &KV[1][(i * 256 + w * 64) * 8]);
        }
        __syncthreads();

        // S^T accumulator init = bias (MFMA C-operand carries it through)
        const float* tb = tb0 + (k0 - s0);
        f32x16 ST;
        #pragma unroll
        for (int r = 0; r < 16; r++)
            ST[r] = tb[(r & 3) + 8 * (r >> 2)];

        // S^T = K @ Q^T + bias: lane holds col q = cid32, rows key = rowmap(r)+4*hi
        #pragma unroll
        for (int s = 0; s < 4; s++) {
            bf16x8 kf = *(const bf16x8*)&KV[0][krow * 64 + (((s * 2 + hi) ^ kxor) * 8)];
            ST = __builtin_amdgcn_mfma_f32_32x32x16_bf16(kf, qf[s], ST, 0, 0, 0);
        }

        // p = exp(S + bias); pack adjacent-key pairs to bf16 dwords
        unsigned u[4][2];
        #pragma unroll
        for (int m = 0; m < 4; m++) {
            u[m][0] = cvtpk(__expf(ST[4 * m + 0]), __expf(ST[4 * m + 1]));
            u[m][1] = cvtpk(__expf(ST[4 * m + 2]), __expf(ST[4 * m + 3]));
        }

        // per 16-key step: assemble PV A-fragment in-register (2 permlane32_swap)
        #pragma unroll
        for (int s2 = 0; s2 < 2; s2++) {
            unsigned x0 = u[2 * s2][0], x1 = u[2 * s2][1];
            unsigned y0 = u[2 * s2 + 1][0], y1 = u[2 * s2 + 1][1];
            asm("v_permlane32_swap_b32 %0, %1" : "+v"(x0), "+v"(y0));
            asm("v_permlane32_swap_b32 %0, %1" : "+v"(x1), "+v"(y1));
            union { unsigned d[4]; bf16x8 v; } pa;
            pa.d[0] = x0; pa.d[1] = x1; pa.d[2] = y0; pa.d[3] = y1;

            // l += P @ 1
            Lacc = __builtin_amdgcn_mfma_f32_32x32x16_bf16(pa.v, vones, Lacc, 0, 0, 0);
            // O += P @ V
            #pragma unroll
            for (int dt = 0; dt < 2; dt++) {
                int drow = dt * 32 + cid32;
                bf16x8 vf = *(const bf16x8*)&KV[1][drow * 64 +
                                (((wk * 4 + s2 * 2 + hi) ^ (drow & 7)) * 8)];
                Oacc[dt] = __builtin_amdgcn_mfma_f32_32x32x16_bf16(pa.v, vf, Oacc[dt], 0, 0, 0);
            }
        }
    }

    // ---- combine the two key-halves (wk) via LDS, write partials ----
    __syncthreads();
    float* Osh = (float*)&KV[0][0];   // 2*32*64 f32 = 16 KB, KV dead now
    if (wk == 0) {
        #pragma unroll
        for (int dt = 0; dt < 2; dt++)
            #pragma unroll
            for (int r = 0; r < 16; r++) {
                int rloc = (r & 3) + 8 * (r >> 2) + 4 * hi;
                Osh[(wq * 32 + rloc) * 64 + dt * 32 + cid32] = Oacc[dt][r];
            }
        if (cid32 == 0)
            #pragma unroll
            for (int r = 0; r < 16; r++)
                Lsh[wq * 32 + (r & 3) + 8 * (r >> 2) + 4 * hi] = Lacc[r];
    }
    __syncthreads();
    if (wk == 1) {
        #pragma unroll
        for (int r = 0; r < 16; r++) {
            int rloc = (r & 3) + 8 * (r >> 2) + 4 * hi;
            int row = q0 + wq * 32 + rloc;
            if (cid32 == 0)
                Lpart[((size_t)seg * NH + h) * S_LEN + row] = Lacc[r] + Lsh[wq * 32 + rloc];
            #pragma unroll
            for (int dt = 0; dt < 2; dt++) {
                float o = Oacc[dt][r] + Osh[(wq * 32 + rloc) * 64 + dt * 32 + cid32];
                Opart[(size_t)seg * (S_LEN * DMODEL) + (size_t)row * DMODEL
                      + h * 64 + dt * 32 + cid32] = f2bf(o);
            }
        }
    }
}

// ---------------- combine split-K partials: Ctx = (O0+O1)/(l0+l1) ----------------
__global__ __launch_bounds__(256) void attn_reduce(
    const ushort_t* __restrict__ Opart, const float* __restrict__ Lpart,
    ushort_t* __restrict__ Ctx)
{
    int i = blockIdx.x * 256 + threadIdx.x;   // over 2048*1024/8 uint4-of-bf16
    int row = i >> 7;                          // 128 x 8 elems per row
    int h = (i & 127) >> 3;
    float l = Lpart[h * S_LEN + row] + Lpart[(NH + h) * S_LEN + row];
    float inv = 1.f / l;
    uint4 a = ((const uint4*)Opart)[i];
    uint4 b = ((const uint4*)Opart)[i + S_LEN * DMODEL / 8];
    alignas(16) ushort_t oa[8]; *(uint4*)oa = a;
    alignas(16) ushort_t ob[8]; *(uint4*)ob = b;
    alignas(16) ushort_t oc[8];
    #pragma unroll
    for (int j = 0; j < 8; j++) oc[j] = f2bf((bf2f(oa[j]) + bf2f(ob[j])) * inv);
    ((uint4*)Ctx)[i] = *(uint4*)oc;
}

// ---------------- launch ----------------
extern "C" void kernel_launch(void* const* d_in, const int* in_sizes, int n_in,
                              void* d_out, int out_size, void* d_ws, size_t ws_size,
                              hipStream_t stream) {
    const float* X  = (const float*)d_in[0];
    const float* Wq = (const float*)d_in[1];
    const float* Wk = (const float*)d_in[2];
    const float* Wv = (const float*)d_in[3];
    const float* Wo = (const float*)d_in[4];
    const float* rb = (const float*)d_in[5];
    float* out = (float*)d_out;

    ushort_t* ws = (ushort_t*)d_ws;
    const size_t M1 = 1024 * 1024;
    // Region timeline (ushort units, 14M total = 28 MB):
    //  0..2M   Xb (bf16 X)        -> dead after QKV gemm -> Opart seg0/seg1 (0..4M)
    //  2..5M   Wt                 -> dead after QKV gemm -> Opart tail + Lpart
    //  5..6M   Wot                (live until final gemm)
    //  6..12M  QKV                -> dead after attn     -> Ctx at 6..8M
    // 12..14M  Vt                 -> dead after attn
    ushort_t* Xb    = ws;
    ushort_t* Wt    = ws + 2 * M1;
    ushort_t* Wot   = ws + 5 * M1;
    ushort_t* QKV   = ws + 6 * M1;
    ushort_t* Vt    = ws + 12 * M1;
    ushort_t* Opart = ws;                       // 4M ushort (2 segs x 2M), over Xb/Wt
    float*    Lpart = (float*)(ws + 4 * M1);    // 64K floats, within dead Wt region
    ushort_t* Ctx   = ws + 6 * M1;              // 2M ushort, over dead QKV

    cast_x<<<dim3((S_LEN * DMODEL / 4 + 255) / 256), 256, 0, stream>>>(X, Xb, S_LEN * DMODEL / 4);
    wcast<<<dim3(16, 16, 4), 256, 0, stream>>>(Wq, Wk, Wv, Wo, Wt, Wot);
    gemm_bf16<<<dim3(24, 16), 256, 0, stream>>>(Xb, Wt, QKV, S_LEN, 3072, DMODEL);
    vt_trans<<<dim3(32, 16), 256, 0, stream>>>(QKV, Vt);
    attn_mfma<<<dim3(32, 16, 2), 256, 0, stream>>>(QKV, Vt, rb, Opart, Lpart);
    attn_reduce<<<dim3(S_LEN * DMODEL / 8 / 256), 256, 0, stream>>>(Opart, Lpart, Ctx);
    gemm64_f32<<<dim3(16, 32), 256, 0, stream>>>(Ctx, Wot, out, S_LEN, DMODEL, DMODEL);
}